// Round 2
// baseline (794.894 us; speedup 1.0000x reference)
//
#include <hip/hip_runtime.h>
#include <hip/hip_bf16.h>

// Problem constants (GATLayer): B=8, C=2048, IN=OUT=128, H=4, D=32
constexpr int B_  = 8;
constexpr int C_  = 2048;
constexpr int IND = 128;
constexpr int H_  = 4;
constexpr int D_  = 32;
constexpr int M_  = B_ * C_;          // 16384 tokens
constexpr float QSCALE = 0.17677669529663687f;   // 1/sqrt(32)
constexpr float L2E    = 1.4426950408889634f;
constexpr float QL2    = QSCALE * L2E;           // folded into Wt Q-rows

constexpr int KSPLIT = 4;             // global split (Opart = 33.6 MB, ws fits)
constexpr int KPG = C_ / KSPLIT;      // 512 keys per (block, kz)
constexpr int KH  = KPG / 2;          // 256 keys per wave (in-block key split)

typedef __attribute__((ext_vector_type(8))) short short8;
typedef __attribute__((ext_vector_type(4))) short s4t;
typedef __attribute__((ext_vector_type(4))) float f4t;
typedef __attribute__((ext_vector_type(4))) unsigned short us4;

// Device pass has these; host pass doesn't advertise via __has_builtin.
#if __has_builtin(__builtin_amdgcn_mfma_f32_16x16x16bf16_1k)
#define MFMA16(a, b, c) __builtin_amdgcn_mfma_f32_16x16x16bf16_1k(a, b, c, 0, 0, 0)
#else
#define MFMA16(a, b, c) (c)   // host-pass placeholder
#endif
#define MFMA32(a, b, c) __builtin_amdgcn_mfma_f32_16x16x32_bf16(a, b, c, 0, 0, 0)

__device__ __forceinline__ unsigned short f2bf(float f) {
    union { float f; unsigned u; } v; v.f = f;
    unsigned u = v.u + 0x7fffu + ((v.u >> 16) & 1u);   // RNE
    return (unsigned short)(u >> 16);
}

__device__ __forceinline__ s4t pack4_bf16(float p0, float p1, float p2, float p3) {
#if __has_builtin(__builtin_amdgcn_cvt_pk_bf16_f32)
    auto a = __builtin_amdgcn_cvt_pk_bf16_f32(p0, p1);
    auto b = __builtin_amdgcn_cvt_pk_bf16_f32(p2, p3);
    unsigned u[2];
    __builtin_memcpy(&u[0], &a, 4);
    __builtin_memcpy(&u[1], &b, 4);
    s4t pp;
    __builtin_memcpy(&pp, u, 8);
    return pp;
#else
    s4t pp;
    pp[0] = (short)f2bf(p0); pp[1] = (short)f2bf(p1);
    pp[2] = (short)f2bf(p2); pp[3] = (short)f2bf(p3);
    return pp;
#endif
}

__device__ __forceinline__ short8 cvt8(float4 a, float4 b) {
    s4t x = pack4_bf16(a.x, a.y, a.z, a.w);
    s4t y = pack4_bf16(b.x, b.y, b.z, b.w);
    short8 r;
    r[0] = x[0]; r[1] = x[1]; r[2] = x[2]; r[3] = x[3];
    r[4] = y[0]; r[5] = y[1]; r[6] = y[2]; r[7] = y[3];
    return r;
}

// ---------------------------------------------------------------------------
// K0: weight prep. Wtb[512][128] bf16: row n = column n of the fused weight
// [Wq*QL2 | Wk | Wv | Wo].  LDS tile transpose, padded stride.
__global__ __launch_bounds__(256) void prep_w_kernel(
    const float* __restrict__ Wq, const float* __restrict__ Wk,
    const float* __restrict__ Wv, const float* __restrict__ Wo,
    unsigned short* __restrict__ Wtb)
{
    __shared__ unsigned short lds[16][130];
    const int t  = threadIdx.x;
    const int n0 = blockIdx.x * 16;          // 0..511 in steps of 16

    const float* src; int nb; float sc = 1.0f;
    if      (n0 < 128) { src = Wq; nb = n0;       sc = QL2; }
    else if (n0 < 256) { src = Wk; nb = n0 - 128; }
    else if (n0 < 384) { src = Wv; nb = n0 - 256; }
    else               { src = Wo; nb = n0 - 384; }

    const int nn = t & 15, kk = t >> 4;      // kk: 0..15
#pragma unroll
    for (int kb = 0; kb < 8; ++kb) {
        const int k = kb * 16 + kk;
        lds[nn][k] = f2bf(src[k * IND + nb + nn] * sc);
    }
    __syncthreads();
    const int k = t & 127, rr = t >> 7;      // rr: 0..1
#pragma unroll
    for (int it = 0; it < 8; ++it) {
        const int r = it * 2 + rr;
        Wtb[(size_t)(n0 + r) * IND + k] = lds[r][k];
    }
}

// ---------------------------------------------------------------------------
// K1: QKV projection via MFMA. Block = 192 = 3 waves (one per matrix);
// grid (M/16, 2): grid.y splits the 8 N-tiles into two halves -> 6144 waves.
// Q/K computed TRANSPOSED (coalesced 8B row stores); V computed normal ->
// lands directly in Vt[b][d][c] layout.
__global__ __launch_bounds__(192) void qkv_proj_kernel(
    const float* __restrict__ x, const unsigned short* __restrict__ Wtb,
    unsigned short* __restrict__ Qb, unsigned short* __restrict__ Kb,
    unsigned short* __restrict__ Vt)
{
    const int t = threadIdx.x;
    const int w = t >> 6;                // 0:Q 1:K 2:V
    const int l = t & 63;
    const int lo = l & 15, hi = l >> 4;
    const int tok0 = blockIdx.x * 16;
    const int b  = tok0 >> 11;
    const int cb = tok0 & 2047;
    const int tile0 = blockIdx.y * 4;

    // x fragments: lane holds x[tok0+lo][kc*32 + hi*8 .. +8] as bf16
    short8 xb[4];
    const float* xrow = x + (size_t)(tok0 + lo) * IND;
#pragma unroll
    for (int kc = 0; kc < 4; ++kc) {
        const float4 a = *(const float4*)(xrow + kc * 32 + hi * 8);
        const float4 c = *(const float4*)(xrow + kc * 32 + hi * 8 + 4);
        xb[kc] = cvt8(a, c);
    }

    const unsigned short* wbase = Wtb + (size_t)(w * 128) * IND;
#pragma unroll
    for (int tile = 0; tile < 4; ++tile) {
        const int n0 = (tile0 + tile) * 16;
        short8 wf[4];
#pragma unroll
        for (int kc = 0; kc < 4; ++kc)
            wf[kc] = *(const short8*)(wbase + (size_t)(n0 + lo) * IND +
                                      kc * 32 + hi * 8);
        f4t acc = 0.f;
        if (w < 2) {
            // Yt = Wt-rows x x-rows: lane owns token=lo, cols n0+hi*4+r
#pragma unroll
            for (int kc = 0; kc < 4; ++kc) acc = MFMA32(wf[kc], xb[kc], acc);
            us4 v;
#pragma unroll
            for (int r = 0; r < 4; ++r) v[r] = f2bf(acc[r]);
            unsigned short* O = (w == 0) ? Qb : Kb;
            *(us4*)(O + (size_t)(tok0 + lo) * IND + n0 + hi * 4) = v;
        } else {
            // Y = x-rows x W-cols: lane owns d=n0+lo, tokens cb+hi*4+r
#pragma unroll
            for (int kc = 0; kc < 4; ++kc) acc = MFMA32(xb[kc], wf[kc], acc);
            us4 v;
#pragma unroll
            for (int r = 0; r < 4; ++r) v[r] = f2bf(acc[r]);
            *(us4*)(Vt + ((size_t)(b * IND) + n0 + lo) * C_ + cb + hi * 4) = v;
        }
    }
}

// ---------------------------------------------------------------------------
// K2: MFMA flash attention. R9 change: TLP not ILP. R8's deeper register
// pipeline spilled (WRITE_SIZE 34->185 MB of scratch) because the body
// only fits 64 VGPR; but at 64 VGPR the HW hosts 8 waves/SIMD and the R0
// grid only supplied 4 (grid-limited: occupancy counter pinned at 45%).
// So: split each wave's keys across TWO waves (256 keys each) and combine
// the un-normalized partials in LDS (exp-sums are linear: O and l add).
// Block = 256 = 4 waves = 2 q-subtiles x 2 key-halves; grid (C/32, B, 4)
// = 2048 blocks = 8 blocks/CU = 8 waves/SIMD. Workspace unchanged.
// Per-wave pipeline is R0's proven 2-stage (kf+adj one ahead); VGPR = 64,
// enforced by launch_bounds(256,8).
__global__ __launch_bounds__(256, 8) void attn_kernel(
    const unsigned short* __restrict__ Qb, const unsigned short* __restrict__ Kb,
    const unsigned short* __restrict__ Vt, const float* __restrict__ adj,
    float* __restrict__ Opart, float* __restrict__ lpart)
{
    __shared__ float sacc[2][64][33];    // [q-subtile][lane][32 acc + 1 l]

    const int t  = threadIdx.x;
    const int w  = t >> 6;
    const int s  = w >> 1;               // q-subtile (0..1)
    const int kh = w & 1;                // key half (0..1)
    const int l  = t & 63;
    const int lo = l & 15, hi = l >> 4;
    const int b  = blockIdx.y;
    const int kz = blockIdx.z;
    const int q0 = blockIdx.x * 32;
    const int qs = q0 + s * 16 + lo;
    const int k0base = kz * KPG + kh * KH;
    const int NIT = KH / 16;             // 16 stages of 16 keys

    short8 qf[4];
#pragma unroll
    for (int h = 0; h < 4; ++h)
        qf[h] = *(const short8*)(Qb + ((size_t)(b * C_) + qs) * IND + h * 32 + hi * 8);

    f4t acc[4][2];
#pragma unroll
    for (int h = 0; h < 4; ++h) { acc[h][0] = 0.f; acc[h][1] = 0.f; }
    float ls[4] = {0.f, 0.f, 0.f, 0.f};

    const float* adjrow = adj + ((size_t)(b * C_) + qs) * C_ + hi * 4;
    const unsigned short* Krow = Kb + ((size_t)(b * C_) + lo) * IND + hi * 8;
    const unsigned short* Vrow = Vt + ((size_t)(b * IND) + lo) * C_ + hi * 4;

    auto loadKA = [&](int st, short8 kf[4], f4t& av) {
        const int k0 = k0base + st * 16;
#pragma unroll
        for (int h = 0; h < 4; ++h)
            kf[h] = *(const short8*)(Krow + (size_t)k0 * IND + h * 32);
        av = *(const f4t*)(adjrow + k0);
    };

    auto computeS = [&](const short8 kf[4], const f4t av, int st) {
        const int k0 = k0base + st * 16;
        s4t vf[8];
#pragma unroll
        for (int h = 0; h < 4; ++h) {
            vf[h * 2]     = *(const s4t*)(Vrow + (size_t)(h * 32) * C_ + k0);
            vf[h * 2 + 1] = *(const s4t*)(Vrow + (size_t)(h * 32 + 16) * C_ + k0);
        }
#pragma unroll
        for (int h = 0; h < 4; ++h) {
            f4t st4 = MFMA32(kf[h], qf[h], (f4t)0.f);
            float p[4];
#pragma unroll
            for (int r = 0; r < 4; ++r) {
                const float a = st4[r] * av[r];          // adj gate (pre-leaky)
                const float m = fmaxf(a, 0.2f * a);      // LeakyReLU(0.2)
                p[r] = exp2f(m);                         // e^s (L2E pre-folded)
                ls[h] += p[r];
            }
            const s4t pp = pack4_bf16(p[0], p[1], p[2], p[3]);
            acc[h][0] = MFMA16(pp, vf[h * 2], acc[h][0]);
            acc[h][1] = MFMA16(pp, vf[h * 2 + 1], acc[h][1]);
        }
    };

    short8 kfA[4], kfB[4];
    f4t avA, avB;
    loadKA(0, kfA, avA);
    for (int it = 0; it < NIT; it += 2) {
        loadKA(it + 1 < NIT ? it + 1 : it, kfB, avB);
        computeS(kfA, avA, it);
        loadKA(it + 2 < NIT ? it + 2 : NIT - 1, kfA, avA);
        computeS(kfB, avB, it + 1);
    }

    // reduce l over the 4 lane-groups (k quarters) within the wave
#pragma unroll
    for (int h = 0; h < 4; ++h) {
        ls[h] += __shfl_xor(ls[h], 16, 64);
        ls[h] += __shfl_xor(ls[h], 32, 64);
    }

    // each lane holds l for head=hi, q=qs
    const float lw = (hi == 0) ? ls[0] : (hi == 1) ? ls[1] : (hi == 2) ? ls[2] : ls[3];

    // cross-wave combine: key-half 1 publishes, key-half 0 merges + writes
    if (kh == 1) {
#pragma unroll
        for (int h = 0; h < 4; ++h)
#pragma unroll
            for (int dh = 0; dh < 2; ++dh)
#pragma unroll
                for (int r = 0; r < 4; ++r)
                    sacc[s][l][h * 8 + dh * 4 + r] = acc[h][dh][r];
        sacc[s][l][32] = lw;
    }
    __syncthreads();
    if (kh == 0) {
        const size_t BHC   = (size_t)B_ * H_ * C_;
        const size_t obase = (size_t)kz * BHC;

        lpart[obase + (size_t)(b * H_ + hi) * C_ + qs] = lw + sacc[s][l][32];

        // O: PV C-layout: lane owns q = q0+s*16+hi*4+r, d = h*32+dh*16+lo
#pragma unroll
        for (int h = 0; h < 4; ++h) {
            const size_t rb = obase + (size_t)(b * H_ + h) * C_ + q0 + s * 16 + hi * 4;
#pragma unroll
            for (int dh = 0; dh < 2; ++dh)
#pragma unroll
                for (int r = 0; r < 4; ++r)
                    Opart[(rb + r) * D_ + dh * 16 + lo] =
                        acc[h][dh][r] + sacc[s][l][h * 8 + dh * 4 + r];
        }
    }
}

// ---------------------------------------------------------------------------
// K3: combine split-K partials -> AOb (bf16):  AOb = (sum O_kz)/(sum l_kz)
__global__ __launch_bounds__(256) void combine_kernel(
    const float* __restrict__ Opart, const float* __restrict__ lpart,
    unsigned short* __restrict__ AOb)
{
    const int cid = blockIdx.x * 256 + threadIdx.x;   // 0 .. 524287
    const int j   = cid & 7;                          // float4 chunk of D=32
    const int idx = cid >> 3;                         // (b*H+h)*C + q
    const int q  = idx & (C_ - 1);
    const int bh = idx >> 11;
    const int h  = bh & (H_ - 1);
    const int b  = bh >> 2;
    const size_t BHC = (size_t)B_ * H_ * C_;

    float4 acc = {0.f, 0.f, 0.f, 0.f};
    float lsum = 0.f;
#pragma unroll
    for (int kz = 0; kz < KSPLIT; ++kz) {
        const size_t base = (size_t)kz * BHC + idx;
        lsum += lpart[base];
        const float4 v = *(const float4*)(Opart + base * D_ + j * 4);
        acc.x += v.x; acc.y += v.y; acc.z += v.z; acc.w += v.w;
    }
    const float inv = 1.f / lsum;
    us4 o;
    o[0] = f2bf(acc.x * inv); o[1] = f2bf(acc.y * inv);
    o[2] = f2bf(acc.z * inv); o[3] = f2bf(acc.w * inv);
    *(us4*)(AOb + ((size_t)(b * C_) + q) * IND + h * D_ + j * 4) = o;
}

// ---------------------------------------------------------------------------
// K4: output projection via MFMA (transposed-compute -> coalesced float4
// stores with fused bias). Block = 256 = 4 waves = 4 N-quarters; 16 tokens
// per block, grid 1024 -> 4096 waves.
__global__ __launch_bounds__(256) void out_proj_kernel(
    const unsigned short* __restrict__ AOb, const unsigned short* __restrict__ Wtb,
    const float* __restrict__ bo, float* __restrict__ out)
{
    const int t  = threadIdx.x;
    const int w  = t >> 6;               // N-quarter
    const int l  = t & 63;
    const int lo = l & 15, hi = l >> 4;
    const int tok0 = blockIdx.x * 16;

    short8 af[4];
    const unsigned short* arow = AOb + (size_t)(tok0 + lo) * IND;
#pragma unroll
    for (int kc = 0; kc < 4; ++kc)
        af[kc] = *(const short8*)(arow + kc * 32 + hi * 8);

    const unsigned short* wbase = Wtb + (size_t)384 * IND;
#pragma unroll
    for (int tt = 0; tt < 2; ++tt) {
        const int n0 = w * 32 + tt * 16;
        short8 wf[4];
#pragma unroll
        for (int kc = 0; kc < 4; ++kc)
            wf[kc] = *(const short8*)(wbase + (size_t)(n0 + lo) * IND +
                                      kc * 32 + hi * 8);
        f4t acc = 0.f;
#pragma unroll
        for (int kc = 0; kc < 4; ++kc) acc = MFMA32(wf[kc], af[kc], acc);
        const f4t bv = *(const f4t*)(bo + n0 + hi * 4);
        float4 o;
        o.x = acc[0] + bv[0]; o.y = acc[1] + bv[1];
        o.z = acc[2] + bv[2]; o.w = acc[3] + bv[3];
        *(float4*)(out + (size_t)(tok0 + lo) * IND + n0 + hi * 4) = o;
    }
}

// ---------------------------------------------------------------------------
extern "C" void kernel_launch(void* const* d_in, const int* in_sizes, int n_in,
                              void* d_out, int out_size, void* d_ws, size_t ws_size,
                              hipStream_t stream) {
    const float* x   = (const float*)d_in[0];
    const float* adj = (const float*)d_in[1];
    const float* Wq  = (const float*)d_in[2];
    const float* Wk  = (const float*)d_in[3];
    const float* Wv  = (const float*)d_in[4];
    const float* Wo  = (const float*)d_in[5];
    const float* bo  = (const float*)d_in[6];
    float* out = (float*)d_out;

    // workspace (bf16 unless noted): Wtb 128KB; Qb/Kb/Vt 4.2MB each;
    // AOb 4.2MB; Opart fp32 33.6MB; lpart fp32 1MB  -> ~47.5 MB total
    unsigned short* Wtb = (unsigned short*)d_ws;
    unsigned short* Qb  = Wtb + (size_t)512 * IND;
    unsigned short* Kb  = Qb + (size_t)M_ * IND;
    unsigned short* Vt  = Kb + (size_t)M_ * IND;
    unsigned short* AOb = Vt + (size_t)M_ * IND;
    float* Opart = (float*)(AOb + (size_t)M_ * IND);
    float* lpart = Opart + (size_t)KSPLIT * B_ * H_ * C_ * D_;

    hipLaunchKernelGGL(prep_w_kernel, dim3(32), dim3(256), 0, stream,
                       Wq, Wk, Wv, Wo, Wtb);
    hipLaunchKernelGGL(qkv_proj_kernel, dim3(M_ / 16, 2), dim3(192), 0, stream,
                       x, Wtb, Qb, Kb, Vt);
    hipLaunchKernelGGL(attn_kernel, dim3(C_ / 32, B_, KSPLIT), dim3(256), 0, stream,
                       Qb, Kb, Vt, adj, Opart, lpart);
    hipLaunchKernelGGL(combine_kernel, dim3(B_ * H_ * C_ * 8 / 256), dim3(256), 0, stream,
                       Opart, lpart, AOb);
    hipLaunchKernelGGL(out_proj_kernel, dim3(M_ / 16), dim3(256), 0, stream,
                       AOb, Wtb, bo, out);
}

// Round 3
// 464.843 us; speedup vs baseline: 1.7100x; 1.7100x over previous
//
#include <hip/hip_runtime.h>
#include <hip/hip_bf16.h>

// Problem constants (GATLayer): B=8, C=2048, IN=OUT=128, H=4, D=32
constexpr int B_  = 8;
constexpr int C_  = 2048;
constexpr int IND = 128;
constexpr int H_  = 4;
constexpr int D_  = 32;
constexpr int M_  = B_ * C_;          // 16384 tokens
constexpr float QSCALE = 0.17677669529663687f;   // 1/sqrt(32)
constexpr float L2E    = 1.4426950408889634f;
constexpr float QL2    = QSCALE * L2E;           // folded into Wt Q-rows

constexpr int KSPLIT = 4;             // global split (Opart = 33.6 MB, ws fits)
constexpr int KPG = C_ / KSPLIT;      // 512 keys per (block, kz)

typedef __attribute__((ext_vector_type(8))) short short8;
typedef __attribute__((ext_vector_type(4))) short s4t;
typedef __attribute__((ext_vector_type(4))) float f4t;
typedef __attribute__((ext_vector_type(4))) unsigned short us4;

// Device pass has these; host pass doesn't advertise via __has_builtin.
#if __has_builtin(__builtin_amdgcn_mfma_f32_16x16x16bf16_1k)
#define MFMA16(a, b, c) __builtin_amdgcn_mfma_f32_16x16x16bf16_1k(a, b, c, 0, 0, 0)
#else
#define MFMA16(a, b, c) (c)   // host-pass placeholder
#endif
#define MFMA32(a, b, c) __builtin_amdgcn_mfma_f32_16x16x32_bf16(a, b, c, 0, 0, 0)

__device__ __forceinline__ unsigned short f2bf(float f) {
    union { float f; unsigned u; } v; v.f = f;
    unsigned u = v.u + 0x7fffu + ((v.u >> 16) & 1u);   // RNE
    return (unsigned short)(u >> 16);
}

__device__ __forceinline__ s4t pack4_bf16(float p0, float p1, float p2, float p3) {
#if __has_builtin(__builtin_amdgcn_cvt_pk_bf16_f32)
    auto a = __builtin_amdgcn_cvt_pk_bf16_f32(p0, p1);
    auto b = __builtin_amdgcn_cvt_pk_bf16_f32(p2, p3);
    unsigned u[2];
    __builtin_memcpy(&u[0], &a, 4);
    __builtin_memcpy(&u[1], &b, 4);
    s4t pp;
    __builtin_memcpy(&pp, u, 8);
    return pp;
#else
    s4t pp;
    pp[0] = (short)f2bf(p0); pp[1] = (short)f2bf(p1);
    pp[2] = (short)f2bf(p2); pp[3] = (short)f2bf(p3);
    return pp;
#endif
}

__device__ __forceinline__ short8 cvt8(float4 a, float4 b) {
    s4t x = pack4_bf16(a.x, a.y, a.z, a.w);
    s4t y = pack4_bf16(b.x, b.y, b.z, b.w);
    short8 r;
    r[0] = x[0]; r[1] = x[1]; r[2] = x[2]; r[3] = x[3];
    r[4] = y[0]; r[5] = y[1]; r[6] = y[2]; r[7] = y[3];
    return r;
}

// ---------------------------------------------------------------------------
// K0: weight prep. Wtb[512][128] bf16: row n = column n of the fused weight
// [Wq*QL2 | Wk | Wv | Wo].  LDS tile transpose, padded stride.
__global__ __launch_bounds__(256) void prep_w_kernel(
    const float* __restrict__ Wq, const float* __restrict__ Wk,
    const float* __restrict__ Wv, const float* __restrict__ Wo,
    unsigned short* __restrict__ Wtb)
{
    __shared__ unsigned short lds[16][130];
    const int t  = threadIdx.x;
    const int n0 = blockIdx.x * 16;          // 0..511 in steps of 16

    const float* src; int nb; float sc = 1.0f;
    if      (n0 < 128) { src = Wq; nb = n0;       sc = QL2; }
    else if (n0 < 256) { src = Wk; nb = n0 - 128; }
    else if (n0 < 384) { src = Wv; nb = n0 - 256; }
    else               { src = Wo; nb = n0 - 384; }

    const int nn = t & 15, kk = t >> 4;      // kk: 0..15
#pragma unroll
    for (int kb = 0; kb < 8; ++kb) {
        const int k = kb * 16 + kk;
        lds[nn][k] = f2bf(src[k * IND + nb + nn] * sc);
    }
    __syncthreads();
    const int k = t & 127, rr = t >> 7;      // rr: 0..1
#pragma unroll
    for (int it = 0; it < 8; ++it) {
        const int r = it * 2 + rr;
        Wtb[(size_t)(n0 + r) * IND + k] = lds[r][k];
    }
}

// ---------------------------------------------------------------------------
// K1: QKV projection via MFMA. Block = 192 = 3 waves (one per matrix);
// grid (M/16, 2): grid.y splits the 8 N-tiles into two halves -> 6144 waves.
// Q/K computed TRANSPOSED (coalesced 8B row stores); V computed normal ->
// lands directly in Vt[b][d][c] layout.
__global__ __launch_bounds__(192) void qkv_proj_kernel(
    const float* __restrict__ x, const unsigned short* __restrict__ Wtb,
    unsigned short* __restrict__ Qb, unsigned short* __restrict__ Kb,
    unsigned short* __restrict__ Vt)
{
    const int t = threadIdx.x;
    const int w = t >> 6;                // 0:Q 1:K 2:V
    const int l = t & 63;
    const int lo = l & 15, hi = l >> 4;
    const int tok0 = blockIdx.x * 16;
    const int b  = tok0 >> 11;
    const int cb = tok0 & 2047;
    const int tile0 = blockIdx.y * 4;

    // x fragments: lane holds x[tok0+lo][kc*32 + hi*8 .. +8] as bf16
    short8 xb[4];
    const float* xrow = x + (size_t)(tok0 + lo) * IND;
#pragma unroll
    for (int kc = 0; kc < 4; ++kc) {
        const float4 a = *(const float4*)(xrow + kc * 32 + hi * 8);
        const float4 c = *(const float4*)(xrow + kc * 32 + hi * 8 + 4);
        xb[kc] = cvt8(a, c);
    }

    const unsigned short* wbase = Wtb + (size_t)(w * 128) * IND;
#pragma unroll
    for (int tile = 0; tile < 4; ++tile) {
        const int n0 = (tile0 + tile) * 16;
        short8 wf[4];
#pragma unroll
        for (int kc = 0; kc < 4; ++kc)
            wf[kc] = *(const short8*)(wbase + (size_t)(n0 + lo) * IND +
                                      kc * 32 + hi * 8);
        f4t acc = 0.f;
        if (w < 2) {
            // Yt = Wt-rows x x-rows: lane owns token=lo, cols n0+hi*4+r
#pragma unroll
            for (int kc = 0; kc < 4; ++kc) acc = MFMA32(wf[kc], xb[kc], acc);
            us4 v;
#pragma unroll
            for (int r = 0; r < 4; ++r) v[r] = f2bf(acc[r]);
            unsigned short* O = (w == 0) ? Qb : Kb;
            *(us4*)(O + (size_t)(tok0 + lo) * IND + n0 + hi * 4) = v;
        } else {
            // Y = x-rows x W-cols: lane owns d=n0+lo, tokens cb+hi*4+r
#pragma unroll
            for (int kc = 0; kc < 4; ++kc) acc = MFMA32(xb[kc], wf[kc], acc);
            us4 v;
#pragma unroll
            for (int r = 0; r < 4; ++r) v[r] = f2bf(acc[r]);
            *(us4*)(Vt + ((size_t)(b * IND) + n0 + lo) * C_ + cb + hi * 4) = v;
        }
    }
}

// ---------------------------------------------------------------------------
// K2: MFMA flash attention, R0 structure (proven: 64 VGPR, no spill,
// grid 1024 x 4 waves) + R10 change: adj staged via global_load_lds DMA.
// R1/R2 lesson: latency-hiding via registers spills (body needs its full
// ~96-reg footprint); global_load_lds costs ZERO VGPR. Per stage the wave
// needs adj[16q][16k] = 1 KB = exactly one global_load_lds(16B) instr.
// Super-stage = 4 stages (4 DMAs), double-buffered -> DMA leads use by a
// full super (~4 stages of compute) >= ~900 cy HBM latency. vmcnt
// retirement is in-order, so `vmcnt(4)` at super s entry (newest 4 = super
// s+1's DMAs) proves super s landed; also drains compiler K/V register
// loads (harmless: L2-hit). Ring is wave-private -> no barriers.
// LDS layout: lane j's 16B chunk = (c4=j>>4, r=j&15) so readback
// lane(lo,hi) -> [hi][lo] is a contiguous 1KB sweep (2-way aliasing, free).
// Arithmetic bitwise-identical to R0.
__global__ __launch_bounds__(256, 4) void attn_kernel(
    const unsigned short* __restrict__ Qb, const unsigned short* __restrict__ Kb,
    const unsigned short* __restrict__ Vt, const float* __restrict__ adj,
    float* __restrict__ Opart, float* __restrict__ lpart)
{
    // [wave][slot][stage][c4][r][4 floats] = 32 KB
    __shared__ float adjs[4][2][4][4][16][4];

    const int t  = threadIdx.x;
    const int s  = t >> 6;               // wave id = q-subtile (0..3)
    const int l  = t & 63;
    const int lo = l & 15, hi = l >> 4;
    const int b  = blockIdx.y;
    const int kz = blockIdx.z;
    const int q0 = blockIdx.x * 64;
    const int qs = q0 + s * 16 + lo;
    const int k0base = kz * KPG;
    const int NIT  = KPG / 16;           // 32 stages
    const int NSUP = NIT / 4;            // 8 super-stages

    // per-lane DMA source: lane j fetches adj row (q0+s*16+(j&15)),
    // 16B at col offset (j>>4)*4 within the stage's 16-key window
    const float* adjsrc = adj + ((size_t)(b * C_) + q0 + s * 16 + (l & 15)) * C_
                          + k0base + (l >> 4) * 4;

    auto dmaSuper = [&](int sp) {
#pragma unroll
        for (int st = 0; st < 4; ++st) {
            const float* src = adjsrc + (size_t)(sp * 4 + st) * 16;
#if __has_builtin(__builtin_amdgcn_global_load_lds)
            __builtin_amdgcn_global_load_lds(
                (const __attribute__((address_space(1))) unsigned int*)src,
                (__attribute__((address_space(3))) unsigned int*)
                    &adjs[s][sp & 1][st][0][0][0],
                16, 0, 0);
#else
            // host-pass placeholder (never executed)
            *(f4t*)&adjs[s][sp & 1][st][l >> 4][l & 15][0] = *(const f4t*)src;
#endif
        }
    };

    // issue first two super-stages before anything else (maximize lead)
    dmaSuper(0);
    dmaSuper(1);

    short8 qf[4];
#pragma unroll
    for (int h = 0; h < 4; ++h)
        qf[h] = *(const short8*)(Qb + ((size_t)(b * C_) + qs) * IND + h * 32 + hi * 8);

    f4t acc[4][2];
#pragma unroll
    for (int h = 0; h < 4; ++h) { acc[h][0] = 0.f; acc[h][1] = 0.f; }
    float ls[4] = {0.f, 0.f, 0.f, 0.f};

    const unsigned short* Krow = Kb + ((size_t)(b * C_) + lo) * IND + hi * 8;
    const unsigned short* Vrow = Vt + ((size_t)(b * IND) + lo) * C_ + hi * 4;

    auto loadK = [&](int st, short8 kf[4]) {
        const int stc = st < NIT ? st : NIT - 1;
        const int k0 = k0base + stc * 16;
#pragma unroll
        for (int h = 0; h < 4; ++h)
            kf[h] = *(const short8*)(Krow + (size_t)k0 * IND + h * 32);
    };

    auto computeS = [&](const short8 kf[4], int g) {
        const int k0 = k0base + g * 16;
        const f4t av = *(const f4t*)&adjs[s][(g >> 2) & 1][g & 3][hi][lo][0];
        s4t vf[8];
#pragma unroll
        for (int h = 0; h < 4; ++h) {
            vf[h * 2]     = *(const s4t*)(Vrow + (size_t)(h * 32) * C_ + k0);
            vf[h * 2 + 1] = *(const s4t*)(Vrow + (size_t)(h * 32 + 16) * C_ + k0);
        }
#pragma unroll
        for (int h = 0; h < 4; ++h) {
            f4t st4 = MFMA32(kf[h], qf[h], (f4t)0.f);
            float p[4];
#pragma unroll
            for (int r = 0; r < 4; ++r) {
                const float a = st4[r] * av[r];          // adj gate (pre-leaky)
                const float m = fmaxf(a, 0.2f * a);      // LeakyReLU(0.2)
                p[r] = exp2f(m);                         // e^s (L2E pre-folded)
                ls[h] += p[r];
            }
            const s4t pp = pack4_bf16(p[0], p[1], p[2], p[3]);
            acc[h][0] = MFMA16(pp, vf[h * 2], acc[h][0]);
            acc[h][1] = MFMA16(pp, vf[h * 2 + 1], acc[h][1]);
        }
    };

    short8 kfA[4], kfB[4];
    loadK(0, kfA);
    for (int sp = 0; sp < NSUP; ++sp) {
        // super s's 4 DMAs are older than super s+1's 4 -> vmcnt(4) proves
        // them retired. Last super: nothing newer outstanding -> vmcnt(0).
        if (sp + 1 < NSUP) { asm volatile("s_waitcnt vmcnt(4)" ::: "memory"); }
        else               { asm volatile("s_waitcnt vmcnt(0)" ::: "memory"); }
        __builtin_amdgcn_sched_barrier(0);

        const int g = sp * 4;
        loadK(g + 1, kfB);
        computeS(kfA, g);
        loadK(g + 2, kfA);
        computeS(kfB, g + 1);
        loadK(g + 3, kfB);
        computeS(kfA, g + 2);
        loadK(g + 4, kfA);
        computeS(kfB, g + 3);

        // our ds_reads of slot (sp&1) must retire before the DMA for
        // super sp+2 can overwrite it
        asm volatile("s_waitcnt lgkmcnt(0)" ::: "memory");
        __builtin_amdgcn_sched_barrier(0);
        if (sp + 2 < NSUP) dmaSuper(sp + 2);
    }

    // reduce l over the 4 lane-groups (k quarters) within the wave
#pragma unroll
    for (int h = 0; h < 4; ++h) {
        ls[h] += __shfl_xor(ls[h], 16, 64);
        ls[h] += __shfl_xor(ls[h], 32, 64);
    }

    const size_t BHC   = (size_t)B_ * H_ * C_;
    const size_t obase = (size_t)kz * BHC;

    // each lane writes l for head=hi, q=qs
    const float lw = (hi == 0) ? ls[0] : (hi == 1) ? ls[1] : (hi == 2) ? ls[2] : ls[3];
    lpart[obase + (size_t)(b * H_ + hi) * C_ + qs] = lw;

    // O: PV C-layout: lane owns q = q0+s*16+hi*4+r, d = h*32+dh*16+lo
#pragma unroll
    for (int h = 0; h < 4; ++h) {
        const size_t rb = obase + (size_t)(b * H_ + h) * C_ + q0 + s * 16 + hi * 4;
#pragma unroll
        for (int dh = 0; dh < 2; ++dh)
#pragma unroll
            for (int r = 0; r < 4; ++r)
                Opart[(rb + r) * D_ + dh * 16 + lo] = acc[h][dh][r];
    }
}

// ---------------------------------------------------------------------------
// K3: combine split-K partials -> AOb (bf16):  AOb = (sum O_kz)/(sum l_kz)
__global__ __launch_bounds__(256) void combine_kernel(
    const float* __restrict__ Opart, const float* __restrict__ lpart,
    unsigned short* __restrict__ AOb)
{
    const int cid = blockIdx.x * 256 + threadIdx.x;   // 0 .. 524287
    const int j   = cid & 7;                          // float4 chunk of D=32
    const int idx = cid >> 3;                         // (b*H+h)*C + q
    const int q  = idx & (C_ - 1);
    const int bh = idx >> 11;
    const int h  = bh & (H_ - 1);
    const int b  = bh >> 2;
    const size_t BHC = (size_t)B_ * H_ * C_;

    float4 acc = {0.f, 0.f, 0.f, 0.f};
    float lsum = 0.f;
#pragma unroll
    for (int kz = 0; kz < KSPLIT; ++kz) {
        const size_t base = (size_t)kz * BHC + idx;
        lsum += lpart[base];
        const float4 v = *(const float4*)(Opart + base * D_ + j * 4);
        acc.x += v.x; acc.y += v.y; acc.z += v.z; acc.w += v.w;
    }
    const float inv = 1.f / lsum;
    us4 o;
    o[0] = f2bf(acc.x * inv); o[1] = f2bf(acc.y * inv);
    o[2] = f2bf(acc.z * inv); o[3] = f2bf(acc.w * inv);
    *(us4*)(AOb + ((size_t)(b * C_) + q) * IND + h * D_ + j * 4) = o;
}

// ---------------------------------------------------------------------------
// K4: output projection via MFMA (transposed-compute -> coalesced float4
// stores with fused bias). Block = 256 = 4 waves = 4 N-quarters; 16 tokens
// per block, grid 1024 -> 4096 waves.
__global__ __launch_bounds__(256) void out_proj_kernel(
    const unsigned short* __restrict__ AOb, const unsigned short* __restrict__ Wtb,
    const float* __restrict__ bo, float* __restrict__ out)
{
    const int t  = threadIdx.x;
    const int w  = t >> 6;               // N-quarter
    const int l  = t & 63;
    const int lo = l & 15, hi = l >> 4;
    const int tok0 = blockIdx.x * 16;

    short8 af[4];
    const unsigned short* arow = AOb + (size_t)(tok0 + lo) * IND;
#pragma unroll
    for (int kc = 0; kc < 4; ++kc)
        af[kc] = *(const short8*)(arow + kc * 32 + hi * 8);

    const unsigned short* wbase = Wtb + (size_t)384 * IND;
#pragma unroll
    for (int tt = 0; tt < 2; ++tt) {
        const int n0 = w * 32 + tt * 16;
        short8 wf[4];
#pragma unroll
        for (int kc = 0; kc < 4; ++kc)
            wf[kc] = *(const short8*)(wbase + (size_t)(n0 + lo) * IND +
                                      kc * 32 + hi * 8);
        f4t acc = 0.f;
#pragma unroll
        for (int kc = 0; kc < 4; ++kc) acc = MFMA32(wf[kc], af[kc], acc);
        const f4t bv = *(const f4t*)(bo + n0 + hi * 4);
        float4 o;
        o.x = acc[0] + bv[0]; o.y = acc[1] + bv[1];
        o.z = acc[2] + bv[2]; o.w = acc[3] + bv[3];
        *(float4*)(out + (size_t)(tok0 + lo) * IND + n0 + hi * 4) = o;
    }
}

// ---------------------------------------------------------------------------
extern "C" void kernel_launch(void* const* d_in, const int* in_sizes, int n_in,
                              void* d_out, int out_size, void* d_ws, size_t ws_size,
                              hipStream_t stream) {
    const float* x   = (const float*)d_in[0];
    const float* adj = (const float*)d_in[1];
    const float* Wq  = (const float*)d_in[2];
    const float* Wk  = (const float*)d_in[3];
    const float* Wv  = (const float*)d_in[4];
    const float* Wo  = (const float*)d_in[5];
    const float* bo  = (const float*)d_in[6];
    float* out = (float*)d_out;

    // workspace (bf16 unless noted): Wtb 128KB; Qb/Kb/Vt 4.2MB each;
    // AOb 4.2MB; Opart fp32 33.6MB; lpart fp32 1MB  -> ~47.5 MB total
    unsigned short* Wtb = (unsigned short*)d_ws;
    unsigned short* Qb  = Wtb + (size_t)512 * IND;
    unsigned short* Kb  = Qb + (size_t)M_ * IND;
    unsigned short* Vt  = Kb + (size_t)M_ * IND;
    unsigned short* AOb = Vt + (size_t)M_ * IND;
    float* Opart = (float*)(AOb + (size_t)M_ * IND);
    float* lpart = Opart + (size_t)KSPLIT * B_ * H_ * C_ * D_;

    hipLaunchKernelGGL(prep_w_kernel, dim3(32), dim3(256), 0, stream,
                       Wq, Wk, Wv, Wo, Wtb);
    hipLaunchKernelGGL(qkv_proj_kernel, dim3(M_ / 16, 2), dim3(192), 0, stream,
                       x, Wtb, Qb, Kb, Vt);
    hipLaunchKernelGGL(attn_kernel, dim3(C_ / 64, B_, KSPLIT), dim3(256), 0, stream,
                       Qb, Kb, Vt, adj, Opart, lpart);
    hipLaunchKernelGGL(combine_kernel, dim3(B_ * H_ * C_ * 8 / 256), dim3(256), 0, stream,
                       Opart, lpart, AOb);
    hipLaunchKernelGGL(out_proj_kernel, dim3(M_ / 16), dim3(256), 0, stream,
                       AOb, Wtb, bo, out);
}

// Round 5
// 287.050 us; speedup vs baseline: 2.7692x; 1.6194x over previous
//
#include <hip/hip_runtime.h>
#include <hip/hip_bf16.h>

// Problem constants (GATLayer): B=8, C=2048, IN=OUT=128, H=4, D=32
constexpr int B_  = 8;
constexpr int C_  = 2048;
constexpr int IND = 128;
constexpr int H_  = 4;
constexpr int D_  = 32;
constexpr int M_  = B_ * C_;          // 16384 tokens
constexpr float QSCALE = 0.17677669529663687f;   // 1/sqrt(32)
constexpr float L2E    = 1.4426950408889634f;
constexpr float QL2    = QSCALE * L2E;           // folded into Wt Q-rows

constexpr int KSPLIT = 4;             // global split (Opart = 33.6 MB, ws fits)
constexpr int KPG = C_ / KSPLIT;      // 512 keys per (block, kz)

typedef __attribute__((ext_vector_type(8))) short short8;
typedef __attribute__((ext_vector_type(4))) short s4t;
typedef __attribute__((ext_vector_type(4))) float f4t;
typedef __attribute__((ext_vector_type(4))) unsigned short us4;

// Device pass has these; host pass doesn't advertise via __has_builtin.
#if __has_builtin(__builtin_amdgcn_mfma_f32_16x16x16bf16_1k)
#define MFMA16(a, b, c) __builtin_amdgcn_mfma_f32_16x16x16bf16_1k(a, b, c, 0, 0, 0)
#else
#define MFMA16(a, b, c) (c)   // host-pass placeholder
#endif
#define MFMA32(a, b, c) __builtin_amdgcn_mfma_f32_16x16x32_bf16(a, b, c, 0, 0, 0)

__device__ __forceinline__ unsigned short f2bf(float f) {
    union { float f; unsigned u; } v; v.f = f;
    unsigned u = v.u + 0x7fffu + ((v.u >> 16) & 1u);   // RNE
    return (unsigned short)(u >> 16);
}

__device__ __forceinline__ s4t pack4_bf16(float p0, float p1, float p2, float p3) {
#if __has_builtin(__builtin_amdgcn_cvt_pk_bf16_f32)
    auto a = __builtin_amdgcn_cvt_pk_bf16_f32(p0, p1);
    auto b = __builtin_amdgcn_cvt_pk_bf16_f32(p2, p3);
    unsigned u[2];
    __builtin_memcpy(&u[0], &a, 4);
    __builtin_memcpy(&u[1], &b, 4);
    s4t pp;
    __builtin_memcpy(&pp, u, 8);
    return pp;
#else
    s4t pp;
    pp[0] = (short)f2bf(p0); pp[1] = (short)f2bf(p1);
    pp[2] = (short)f2bf(p2); pp[3] = (short)f2bf(p3);
    return pp;
#endif
}

__device__ __forceinline__ short8 cvt8(float4 a, float4 b) {
    s4t x = pack4_bf16(a.x, a.y, a.z, a.w);
    s4t y = pack4_bf16(b.x, b.y, b.z, b.w);
    short8 r;
    r[0] = x[0]; r[1] = x[1]; r[2] = x[2]; r[3] = x[3];
    r[4] = y[0]; r[5] = y[1]; r[6] = y[2]; r[7] = y[3];
    return r;
}

// ---------------------------------------------------------------------------
// K0: weight prep. Wtb[512][128] bf16: row n = column n of the fused weight
// [Wq*QL2 | Wk | Wv | Wo].  LDS tile transpose, padded stride.
__global__ __launch_bounds__(256) void prep_w_kernel(
    const float* __restrict__ Wq, const float* __restrict__ Wk,
    const float* __restrict__ Wv, const float* __restrict__ Wo,
    unsigned short* __restrict__ Wtb)
{
    __shared__ unsigned short lds[16][130];
    const int t  = threadIdx.x;
    const int n0 = blockIdx.x * 16;          // 0..511 in steps of 16

    const float* src; int nb; float sc = 1.0f;
    if      (n0 < 128) { src = Wq; nb = n0;       sc = QL2; }
    else if (n0 < 256) { src = Wk; nb = n0 - 128; }
    else if (n0 < 384) { src = Wv; nb = n0 - 256; }
    else               { src = Wo; nb = n0 - 384; }

    const int nn = t & 15, kk = t >> 4;      // kk: 0..15
#pragma unroll
    for (int kb = 0; kb < 8; ++kb) {
        const int k = kb * 16 + kk;
        lds[nn][k] = f2bf(src[k * IND + nb + nn] * sc);
    }
    __syncthreads();
    const int k = t & 127, rr = t >> 7;      // rr: 0..1
#pragma unroll
    for (int it = 0; it < 8; ++it) {
        const int r = it * 2 + rr;
        Wtb[(size_t)(n0 + r) * IND + k] = lds[r][k];
    }
}

// ---------------------------------------------------------------------------
// K1: QKV projection via MFMA. Block = 192 = 3 waves (one per matrix);
// grid (M/16, 2): grid.y splits the 8 N-tiles into two halves -> 6144 waves.
// Q/K computed TRANSPOSED (coalesced 8B row stores); V computed normal ->
// lands directly in Vt[b][d][c] layout.
__global__ __launch_bounds__(192) void qkv_proj_kernel(
    const float* __restrict__ x, const unsigned short* __restrict__ Wtb,
    unsigned short* __restrict__ Qb, unsigned short* __restrict__ Kb,
    unsigned short* __restrict__ Vt)
{
    const int t = threadIdx.x;
    const int w = t >> 6;                // 0:Q 1:K 2:V
    const int l = t & 63;
    const int lo = l & 15, hi = l >> 4;
    const int tok0 = blockIdx.x * 16;
    const int b  = tok0 >> 11;
    const int cb = tok0 & 2047;
    const int tile0 = blockIdx.y * 4;

    // x fragments: lane holds x[tok0+lo][kc*32 + hi*8 .. +8] as bf16
    short8 xb[4];
    const float* xrow = x + (size_t)(tok0 + lo) * IND;
#pragma unroll
    for (int kc = 0; kc < 4; ++kc) {
        const float4 a = *(const float4*)(xrow + kc * 32 + hi * 8);
        const float4 c = *(const float4*)(xrow + kc * 32 + hi * 8 + 4);
        xb[kc] = cvt8(a, c);
    }

    const unsigned short* wbase = Wtb + (size_t)(w * 128) * IND;
#pragma unroll
    for (int tile = 0; tile < 4; ++tile) {
        const int n0 = (tile0 + tile) * 16;
        short8 wf[4];
#pragma unroll
        for (int kc = 0; kc < 4; ++kc)
            wf[kc] = *(const short8*)(wbase + (size_t)(n0 + lo) * IND +
                                      kc * 32 + hi * 8);
        f4t acc = 0.f;
        if (w < 2) {
            // Yt = Wt-rows x x-rows: lane owns token=lo, cols n0+hi*4+r
#pragma unroll
            for (int kc = 0; kc < 4; ++kc) acc = MFMA32(wf[kc], xb[kc], acc);
            us4 v;
#pragma unroll
            for (int r = 0; r < 4; ++r) v[r] = f2bf(acc[r]);
            unsigned short* O = (w == 0) ? Qb : Kb;
            *(us4*)(O + (size_t)(tok0 + lo) * IND + n0 + hi * 4) = v;
        } else {
            // Y = x-rows x W-cols: lane owns d=n0+lo, tokens cb+hi*4+r
#pragma unroll
            for (int kc = 0; kc < 4; ++kc) acc = MFMA32(xb[kc], wf[kc], acc);
            us4 v;
#pragma unroll
            for (int r = 0; r < 4; ++r) v[r] = f2bf(acc[r]);
            *(us4*)(Vt + ((size_t)(b * IND) + n0 + lo) * C_ + cb + hi * 4) = v;
        }
    }
}

// ---------------------------------------------------------------------------
// K2: MFMA flash attention, "separate the counters" structure (R11),
// hardened after R4's infra-failed run (R12):
//  * raw s_barrier instead of __syncthreads() -- __syncthreads lowers to
//    s_waitcnt vmcnt(0) before s_barrier, which would drain the in-flight
//    next-chunk DMAs and defeat the counted-vmcnt pipeline;
//  * sched_barrier(0) fences pin prologue issue order (qf -> stage0 ->
//    stage1) so vmcnt(6) at c=0 provably retires qf+stage(0).
// Rationale (R0-R3 chain): the hot loop mixed L2-hit K/V register loads
// with the cold-HBM adj stream in ONE in-order vmcnt queue, so the wait
// before each V use retired the adj prefetch -> full HBM latency exposed
// every stage; register-side fixes all spilled (body at the VGPR edge).
// Now ALL three streams (K, V, adj) are staged by global_load_lds (vmcnt,
// zero VGPR) and consumed by ds_read (lgkmcnt). The steady loop's only
// vmcnt wait is the counted vmcnt(6) at chunk top: retires chunk c's 6
// DMAs, keeps chunk c+1's 6 in flight.
// Geometry: 16 chunks x 32 keys; per chunk K 8KB + V 8KB + adj 8KB,
// double-buffered = 48KB LDS -> 3 blocks/CU. LDS already caps occupancy,
// so __launch_bounds__(256,3) grants ~170 unified regs at no cost ->
// removes the spill cliff. XOR swizzles (G4/T2) applied on the GLOBAL
// source address (DMA dest must stay linear), inverse XOR on ds_read.
// Math is bit-identical to R0.
__global__ __launch_bounds__(256, 3) void attn_kernel(
    const unsigned short* __restrict__ Qb, const unsigned short* __restrict__ Kb,
    const unsigned short* __restrict__ Vt, const float* __restrict__ adj,
    float* __restrict__ Opart, float* __restrict__ lpart)
{
    __shared__ __align__(16) char Ksm[2][8192];   // [key 0..31][128 d bf16]
    __shared__ __align__(16) char Vsm[2][8192];   // [d 0..127][32 keys bf16]
    __shared__ __align__(16) char Asm[2][8192];   // [q 0..63][32 keys f32]

    const int t  = threadIdx.x;
    const int s  = t >> 6;               // wave id = q-subtile (0..3)
    const int l  = t & 63;
    const int lo = l & 15, hi = l >> 4;
    const int b  = blockIdx.y;
    const int kz = blockIdx.z;
    const int q0 = blockIdx.x * 64;
    const int qs = q0 + s * 16 + lo;
    const int kzoff = kz * KPG;
    const int NCH = KPG / 32;            // 16 chunks

    // consumption swizzle constants
    const int x7 = (lo & 7) << 4;
    const int x3 = (lo & 3) << 4;

    // ---- staging source addresses (per lane, bytes). Each wave stages
    // instrs {2s, 2s+1} of each stream (6 DMAs/chunk/wave, 1KB each). ----
    // K: instr i covers chunk-local keys 4i..4i+3 (4 rows x 256B)
    const int keyA = s * 8 + (l >> 4);
    const int keyB = keyA + 4;
    const char* srcK_A = (const char*)Kb + ((size_t)(b * C_ + kzoff) + keyA) * 256
                         + (((l & 15) * 16) ^ ((keyA & 7) << 4));
    const char* srcK_B = (const char*)Kb + ((size_t)(b * C_ + kzoff) + keyB) * 256
                         + (((l & 15) * 16) ^ ((keyB & 7) << 4));
    // V: instr i covers d rows 16i..16i+15 (16 rows x 64B)
    const int dA = s * 32 + (l >> 2);
    const int dB = dA + 16;
    const char* srcV_A = (const char*)Vt + (size_t)(b * IND + dA) * (C_ * 2)
                         + (size_t)kzoff * 2
                         + (((l & 3) * 16) ^ ((dA & 3) << 4));
    const char* srcV_B = (const char*)Vt + (size_t)(b * IND + dB) * (C_ * 2)
                         + (size_t)kzoff * 2
                         + (((l & 3) * 16) ^ ((dB & 3) << 4));
    // adj: instr i covers q rows 8i..8i+7 (8 rows x 128B)
    const int qA = s * 16 + (l >> 3);
    const int qB = qA + 8;
    const char* srcA_A = (const char*)adj + ((size_t)(b * C_ + q0 + qA) * C_ + kzoff) * 4
                         + (((l & 7) * 16) ^ ((qA & 7) << 4));
    const char* srcA_B = (const char*)adj + ((size_t)(b * C_ + q0 + qB) * C_ + kzoff) * 4
                         + (((l & 7) * 16) ^ ((qB & 7) << 4));

#if __has_builtin(__builtin_amdgcn_global_load_lds)
#define GLL(gp, lp) __builtin_amdgcn_global_load_lds( \
    (const __attribute__((address_space(1))) unsigned int*)(gp), \
    (__attribute__((address_space(3))) unsigned int*)(lp), 16, 0, 0)
#else
#define GLL(gp, lp) (void)(gp)   // host-pass placeholder
#endif

    auto stage = [&](int c, int buf) {
        GLL(srcK_A + (size_t)c * 8192, Ksm[buf] + (2 * s)     * 1024);
        GLL(srcK_B + (size_t)c * 8192, Ksm[buf] + (2 * s + 1) * 1024);
        GLL(srcV_A + (size_t)c * 64,   Vsm[buf] + (2 * s)     * 1024);
        GLL(srcV_B + (size_t)c * 64,   Vsm[buf] + (2 * s + 1) * 1024);
        GLL(srcA_A + (size_t)c * 128,  Asm[buf] + (2 * s)     * 1024);
        GLL(srcA_B + (size_t)c * 128,  Asm[buf] + (2 * s + 1) * 1024);
    };

    // qf loaded FIRST, then stage(0), then stage(1); sched_barrier(0)
    // fences pin this issue order so the c=0 vmcnt(6) retires exactly
    // qf(4) + stage0(6), keeping stage1's 6 in flight.
    short8 qf[4];
#pragma unroll
    for (int h = 0; h < 4; ++h)
        qf[h] = *(const short8*)(Qb + ((size_t)(b * C_) + qs) * IND + h * 32 + hi * 8);
    __builtin_amdgcn_sched_barrier(0);
    stage(0, 0);
    __builtin_amdgcn_sched_barrier(0);
    stage(1, 1);
    __builtin_amdgcn_sched_barrier(0);

    f4t acc[4][2];
#pragma unroll
    for (int h = 0; h < 4; ++h) { acc[h][0] = 0.f; acc[h][1] = 0.f; }
    float ls[4] = {0.f, 0.f, 0.f, 0.f};

    auto computeC = [&](int buf, int st) {
        const char* Kl = Ksm[buf];
        const char* Vl = Vsm[buf];
        const char* Al = Asm[buf];
        short8 kf[4];
#pragma unroll
        for (int h = 0; h < 4; ++h)
            kf[h] = *(const short8*)(Kl + (st * 16 + lo) * 256 +
                                     ((h * 64 + hi * 16) ^ x7));
        s4t vf[8];
#pragma unroll
        for (int h = 0; h < 4; ++h) {
            vf[h * 2]     = *(const s4t*)(Vl + (h * 32 + lo) * 64 +
                                          ((st * 32 + hi * 8) ^ x3));
            vf[h * 2 + 1] = *(const s4t*)(Vl + (h * 32 + 16 + lo) * 64 +
                                          ((st * 32 + hi * 8) ^ x3));
        }
        const f4t av = *(const f4t*)(Al + (s * 16 + lo) * 128 +
                                     ((st * 64 + hi * 16) ^ x7));
#pragma unroll
        for (int h = 0; h < 4; ++h) {
            f4t st4 = MFMA32(kf[h], qf[h], (f4t)0.f);
            float p[4];
#pragma unroll
            for (int r = 0; r < 4; ++r) {
                const float a = st4[r] * av[r];          // adj gate (pre-leaky)
                const float m = fmaxf(a, 0.2f * a);      // LeakyReLU(0.2)
                p[r] = exp2f(m);                         // e^s (L2E pre-folded)
                ls[h] += p[r];
            }
            const s4t pp = pack4_bf16(p[0], p[1], p[2], p[3]);
            acc[h][0] = MFMA16(pp, vf[h * 2], acc[h][0]);
            acc[h][1] = MFMA16(pp, vf[h * 2 + 1], acc[h][1]);
        }
    };

    for (int c = 0; c < NCH; ++c) {
        // counted wait: retire chunk c's 6 DMAs (older), keep chunk c+1's
        // 6 in flight. Last chunk: drain. Then raw barrier (NOT
        // __syncthreads: that would drain vmcnt(0)) -- all waves' chunk-c
        // DMAs have landed once every wave passed its own vmcnt wait.
        if (c + 1 < NCH) { asm volatile("s_waitcnt vmcnt(6)" ::: "memory"); }
        else             { asm volatile("s_waitcnt vmcnt(0)" ::: "memory"); }
        __builtin_amdgcn_sched_barrier(0);
        __builtin_amdgcn_s_barrier();
        __builtin_amdgcn_sched_barrier(0);

        computeC(c & 1, 0);
        computeC(c & 1, 1);

        // all our ds_reads of buf[c&1] retired (results consumed), fence
        // and barrier before any wave's DMA may overwrite buf[c&1]
        asm volatile("s_waitcnt lgkmcnt(0)" ::: "memory");
        __builtin_amdgcn_sched_barrier(0);
        __builtin_amdgcn_s_barrier();
        __builtin_amdgcn_sched_barrier(0);
        if (c + 2 < NCH) stage(c + 2, c & 1);
    }

    // reduce l over the 4 lane-groups (k quarters) within the wave
#pragma unroll
    for (int h = 0; h < 4; ++h) {
        ls[h] += __shfl_xor(ls[h], 16, 64);
        ls[h] += __shfl_xor(ls[h], 32, 64);
    }

    const size_t BHC   = (size_t)B_ * H_ * C_;
    const size_t obase = (size_t)kz * BHC;

    // each lane writes l for head=hi, q=qs
    const float lw = (hi == 0) ? ls[0] : (hi == 1) ? ls[1] : (hi == 2) ? ls[2] : ls[3];
    lpart[obase + (size_t)(b * H_ + hi) * C_ + qs] = lw;

    // O: PV C-layout: lane owns q = q0+s*16+hi*4+r, d = h*32+dh*16+lo
#pragma unroll
    for (int h = 0; h < 4; ++h) {
        const size_t rb = obase + (size_t)(b * H_ + h) * C_ + q0 + s * 16 + hi * 4;
#pragma unroll
        for (int dh = 0; dh < 2; ++dh)
#pragma unroll
            for (int r = 0; r < 4; ++r)
                Opart[(rb + r) * D_ + dh * 16 + lo] = acc[h][dh][r];
    }
#undef GLL
}

// ---------------------------------------------------------------------------
// K3: combine split-K partials -> AOb (bf16):  AOb = (sum O_kz)/(sum l_kz)
__global__ __launch_bounds__(256) void combine_kernel(
    const float* __restrict__ Opart, const float* __restrict__ lpart,
    unsigned short* __restrict__ AOb)
{
    const int cid = blockIdx.x * 256 + threadIdx.x;   // 0 .. 524287
    const int j   = cid & 7;                          // float4 chunk of D=32
    const int idx = cid >> 3;                         // (b*H+h)*C + q
    const int q  = idx & (C_ - 1);
    const int bh = idx >> 11;
    const int h  = bh & (H_ - 1);
    const int b  = bh >> 2;
    const size_t BHC = (size_t)B_ * H_ * C_;

    float4 acc = {0.f, 0.f, 0.f, 0.f};
    float lsum = 0.f;
#pragma unroll
    for (int kz = 0; kz < KSPLIT; ++kz) {
        const size_t base = (size_t)kz * BHC + idx;
        lsum += lpart[base];
        const float4 v = *(const float4*)(Opart + base * D_ + j * 4);
        acc.x += v.x; acc.y += v.y; acc.z += v.z; acc.w += v.w;
    }
    const float inv = 1.f / lsum;
    us4 o;
    o[0] = f2bf(acc.x * inv); o[1] = f2bf(acc.y * inv);
    o[2] = f2bf(acc.z * inv); o[3] = f2bf(acc.w * inv);
    *(us4*)(AOb + ((size_t)(b * C_) + q) * IND + h * D_ + j * 4) = o;
}

// ---------------------------------------------------------------------------
// K4: output projection via MFMA (transposed-compute -> coalesced float4
// stores with fused bias). Block = 256 = 4 waves = 4 N-quarters; 16 tokens
// per block, grid 1024 -> 4096 waves.
__global__ __launch_bounds__(256) void out_proj_kernel(
    const unsigned short* __restrict__ AOb, const unsigned short* __restrict__ Wtb,
    const float* __restrict__ bo, float* __restrict__ out)
{
    const int t  = threadIdx.x;
    const int w  = t >> 6;               // N-quarter
    const int l  = t & 63;
    const int lo = l & 15, hi = l >> 4;
    const int tok0 = blockIdx.x * 16;

    short8 af[4];
    const unsigned short* arow = AOb + (size_t)(tok0 + lo) * IND;
#pragma unroll
    for (int kc = 0; kc < 4; ++kc)
        af[kc] = *(const short8*)(arow + kc * 32 + hi * 8);

    const unsigned short* wbase = Wtb + (size_t)384 * IND;
#pragma unroll
    for (int tt = 0; tt < 2; ++tt) {
        const int n0 = w * 32 + tt * 16;
        short8 wf[4];
#pragma unroll
        for (int kc = 0; kc < 4; ++kc)
            wf[kc] = *(const short8*)(wbase + (size_t)(n0 + lo) * IND +
                                      kc * 32 + hi * 8);
        f4t acc = 0.f;
#pragma unroll
        for (int kc = 0; kc < 4; ++kc) acc = MFMA32(wf[kc], af[kc], acc);
        const f4t bv = *(const f4t*)(bo + n0 + hi * 4);
        float4 o;
        o.x = acc[0] + bv[0]; o.y = acc[1] + bv[1];
        o.z = acc[2] + bv[2]; o.w = acc[3] + bv[3];
        *(float4*)(out + (size_t)(tok0 + lo) * IND + n0 + hi * 4) = o;
    }
}

// ---------------------------------------------------------------------------
extern "C" void kernel_launch(void* const* d_in, const int* in_sizes, int n_in,
                              void* d_out, int out_size, void* d_ws, size_t ws_size,
                              hipStream_t stream) {
    const float* x   = (const float*)d_in[0];
    const float* adj = (const float*)d_in[1];
    const float* Wq  = (const float*)d_in[2];
    const float* Wk  = (const float*)d_in[3];
    const float* Wv  = (const float*)d_in[4];
    const float* Wo  = (const float*)d_in[5];
    const float* bo  = (const float*)d_in[6];
    float* out = (float*)d_out;

    // workspace (bf16 unless noted): Wtb 128KB; Qb/Kb/Vt 4.2MB each;
    // AOb 4.2MB; Opart fp32 33.6MB; lpart fp32 1MB  -> ~47.5 MB total
    unsigned short* Wtb = (unsigned short*)d_ws;
    unsigned short* Qb  = Wtb + (size_t)512 * IND;
    unsigned short* Kb  = Qb + (size_t)M_ * IND;
    unsigned short* Vt  = Kb + (size_t)M_ * IND;
    unsigned short* AOb = Vt + (size_t)M_ * IND;
    float* Opart = (float*)(AOb + (size_t)M_ * IND);
    float* lpart = Opart + (size_t)KSPLIT * B_ * H_ * C_ * D_;

    hipLaunchKernelGGL(prep_w_kernel, dim3(32), dim3(256), 0, stream,
                       Wq, Wk, Wv, Wo, Wtb);
    hipLaunchKernelGGL(qkv_proj_kernel, dim3(M_ / 16, 2), dim3(192), 0, stream,
                       x, Wtb, Qb, Kb, Vt);
    hipLaunchKernelGGL(attn_kernel, dim3(C_ / 64, B_, KSPLIT), dim3(256), 0, stream,
                       Qb, Kb, Vt, adj, Opart, lpart);
    hipLaunchKernelGGL(combine_kernel, dim3(B_ * H_ * C_ * 8 / 256), dim3(256), 0, stream,
                       Opart, lpart, AOb);
    hipLaunchKernelGGL(out_proj_kernel, dim3(M_ / 16), dim3(256), 0, stream,
                       AOb, Wtb, bo, out);
}

// Round 6
// 286.472 us; speedup vs baseline: 2.7748x; 1.0020x over previous
//
#include <hip/hip_runtime.h>
#include <hip/hip_bf16.h>

// Problem constants (GATLayer): B=8, C=2048, IN=OUT=128, H=4, D=32
constexpr int B_  = 8;
constexpr int C_  = 2048;
constexpr int IND = 128;
constexpr int H_  = 4;
constexpr int D_  = 32;
constexpr int M_  = B_ * C_;          // 16384 tokens
constexpr float QSCALE = 0.17677669529663687f;   // 1/sqrt(32)
constexpr float L2E    = 1.4426950408889634f;
constexpr float QL2    = QSCALE * L2E;           // folded into Wt Q-rows

constexpr int KSPLIT = 4;             // global split (Opart = 33.6 MB, ws fits)
constexpr int KPG = C_ / KSPLIT;      // 512 keys per (block, kz)

typedef __attribute__((ext_vector_type(8))) short short8;
typedef __attribute__((ext_vector_type(4))) short s4t;
typedef __attribute__((ext_vector_type(4))) float f4t;
typedef __attribute__((ext_vector_type(4))) unsigned short us4;

// Device pass has these; host pass doesn't advertise via __has_builtin.
#if __has_builtin(__builtin_amdgcn_mfma_f32_16x16x16bf16_1k)
#define MFMA16(a, b, c) __builtin_amdgcn_mfma_f32_16x16x16bf16_1k(a, b, c, 0, 0, 0)
#else
#define MFMA16(a, b, c) (c)   // host-pass placeholder
#endif
#define MFMA32(a, b, c) __builtin_amdgcn_mfma_f32_16x16x32_bf16(a, b, c, 0, 0, 0)

__device__ __forceinline__ unsigned short f2bf(float f) {
    union { float f; unsigned u; } v; v.f = f;
    unsigned u = v.u + 0x7fffu + ((v.u >> 16) & 1u);   // RNE
    return (unsigned short)(u >> 16);
}

__device__ __forceinline__ s4t pack4_bf16(float p0, float p1, float p2, float p3) {
#if __has_builtin(__builtin_amdgcn_cvt_pk_bf16_f32)
    auto a = __builtin_amdgcn_cvt_pk_bf16_f32(p0, p1);
    auto b = __builtin_amdgcn_cvt_pk_bf16_f32(p2, p3);
    unsigned u[2];
    __builtin_memcpy(&u[0], &a, 4);
    __builtin_memcpy(&u[1], &b, 4);
    s4t pp;
    __builtin_memcpy(&pp, u, 8);
    return pp;
#else
    s4t pp;
    pp[0] = (short)f2bf(p0); pp[1] = (short)f2bf(p1);
    pp[2] = (short)f2bf(p2); pp[3] = (short)f2bf(p3);
    return pp;
#endif
}

__device__ __forceinline__ short8 cvt8(float4 a, float4 b) {
    s4t x = pack4_bf16(a.x, a.y, a.z, a.w);
    s4t y = pack4_bf16(b.x, b.y, b.z, b.w);
    short8 r;
    r[0] = x[0]; r[1] = x[1]; r[2] = x[2]; r[3] = x[3];
    r[4] = y[0]; r[5] = y[1]; r[6] = y[2]; r[7] = y[3];
    return r;
}

// ---------------------------------------------------------------------------
// K0: weight prep. Wtb[512][128] bf16: row n = column n of the fused weight
// [Wq*QL2 | Wk | Wv | Wo].  LDS tile transpose, padded stride.
__global__ __launch_bounds__(256) void prep_w_kernel(
    const float* __restrict__ Wq, const float* __restrict__ Wk,
    const float* __restrict__ Wv, const float* __restrict__ Wo,
    unsigned short* __restrict__ Wtb)
{
    __shared__ unsigned short lds[16][130];
    const int t  = threadIdx.x;
    const int n0 = blockIdx.x * 16;          // 0..511 in steps of 16

    const float* src; int nb; float sc = 1.0f;
    if      (n0 < 128) { src = Wq; nb = n0;       sc = QL2; }
    else if (n0 < 256) { src = Wk; nb = n0 - 128; }
    else if (n0 < 384) { src = Wv; nb = n0 - 256; }
    else               { src = Wo; nb = n0 - 384; }

    const int nn = t & 15, kk = t >> 4;      // kk: 0..15
#pragma unroll
    for (int kb = 0; kb < 8; ++kb) {
        const int k = kb * 16 + kk;
        lds[nn][k] = f2bf(src[k * IND + nb + nn] * sc);
    }
    __syncthreads();
    const int k = t & 127, rr = t >> 7;      // rr: 0..1
#pragma unroll
    for (int it = 0; it < 8; ++it) {
        const int r = it * 2 + rr;
        Wtb[(size_t)(n0 + r) * IND + k] = lds[r][k];
    }
}

// ---------------------------------------------------------------------------
// K1: QKV projection via MFMA. Block = 192 = 3 waves (one per matrix);
// grid (M/16, 2): grid.y splits the 8 N-tiles into two halves -> 6144 waves.
// Q/K computed TRANSPOSED (coalesced 8B row stores); V computed normal ->
// lands directly in Vt[b][d][c] layout.
__global__ __launch_bounds__(192) void qkv_proj_kernel(
    const float* __restrict__ x, const unsigned short* __restrict__ Wtb,
    unsigned short* __restrict__ Qb, unsigned short* __restrict__ Kb,
    unsigned short* __restrict__ Vt)
{
    const int t = threadIdx.x;
    const int w = t >> 6;                // 0:Q 1:K 2:V
    const int l = t & 63;
    const int lo = l & 15, hi = l >> 4;
    const int tok0 = blockIdx.x * 16;
    const int b  = tok0 >> 11;
    const int cb = tok0 & 2047;
    const int tile0 = blockIdx.y * 4;

    // x fragments: lane holds x[tok0+lo][kc*32 + hi*8 .. +8] as bf16
    short8 xb[4];
    const float* xrow = x + (size_t)(tok0 + lo) * IND;
#pragma unroll
    for (int kc = 0; kc < 4; ++kc) {
        const float4 a = *(const float4*)(xrow + kc * 32 + hi * 8);
        const float4 c = *(const float4*)(xrow + kc * 32 + hi * 8 + 4);
        xb[kc] = cvt8(a, c);
    }

    const unsigned short* wbase = Wtb + (size_t)(w * 128) * IND;
#pragma unroll
    for (int tile = 0; tile < 4; ++tile) {
        const int n0 = (tile0 + tile) * 16;
        short8 wf[4];
#pragma unroll
        for (int kc = 0; kc < 4; ++kc)
            wf[kc] = *(const short8*)(wbase + (size_t)(n0 + lo) * IND +
                                      kc * 32 + hi * 8);
        f4t acc = 0.f;
        if (w < 2) {
            // Yt = Wt-rows x x-rows: lane owns token=lo, cols n0+hi*4+r
#pragma unroll
            for (int kc = 0; kc < 4; ++kc) acc = MFMA32(wf[kc], xb[kc], acc);
            us4 v;
#pragma unroll
            for (int r = 0; r < 4; ++r) v[r] = f2bf(acc[r]);
            unsigned short* O = (w == 0) ? Qb : Kb;
            *(us4*)(O + (size_t)(tok0 + lo) * IND + n0 + hi * 4) = v;
        } else {
            // Y = x-rows x W-cols: lane owns d=n0+lo, tokens cb+hi*4+r
#pragma unroll
            for (int kc = 0; kc < 4; ++kc) acc = MFMA32(xb[kc], wf[kc], acc);
            us4 v;
#pragma unroll
            for (int r = 0; r < 4; ++r) v[r] = f2bf(acc[r]);
            *(us4*)(Vt + ((size_t)(b * IND) + n0 + lo) * C_ + cb + hi * 4) = v;
        }
    }
}

// ---------------------------------------------------------------------------
// K2: MFMA flash attention, "separate the counters" (proven R5: 106 us,
// no spill) + R13 change: 16-key chunks -> 24 KB LDS so ALL 4 blocks/CU
// of the grid are co-resident (R5: 48 KB capped residency at 3 of 4
// blocks -> occupancy 22.8%, VALU 50%, straggler round). Per chunk each
// wave issues 3 DMAs (K 1KB, V 1KB, adj 1KB); steady-state wait is the
// counted vmcnt(3) at chunk top (chunk c retires, chunk c+1 stays in
// flight). Consumers are ds_read (lgkmcnt) -- the DMA queue is never
// drained in the loop. Raw s_barrier (NOT __syncthreads: that waits
// vmcnt(0) and would kill the pipeline).
// Bank geometry (G4): K rows 256B -> XOR-swizzle ((row&7)<<4) applied on
// the pre-swizzled GLOBAL source (DMA dest must stay linear), inverse on
// the ds_read. V rows are now 32B and adj rows 64B -> reads spread over
// all bank slots naturally, NO swizzle (R5's 64B/128B rows + ad-hoc
// swizzles caused 14.7M conflict cycles).
// Math is bit-identical to R0/R5.
__global__ __launch_bounds__(256, 4) void attn_kernel(
    const unsigned short* __restrict__ Qb, const unsigned short* __restrict__ Kb,
    const unsigned short* __restrict__ Vt, const float* __restrict__ adj,
    float* __restrict__ Opart, float* __restrict__ lpart)
{
    __shared__ __align__(16) char Ksm[2][4096];   // [key 0..15][128 d bf16]
    __shared__ __align__(16) char Vsm[2][4096];   // [d 0..127][16 keys bf16]
    __shared__ __align__(16) char Asm[2][4096];   // [q 0..63][16 keys f32]

    const int t  = threadIdx.x;
    const int s  = t >> 6;               // wave id = q-subtile (0..3)
    const int l  = t & 63;
    const int lo = l & 15, hi = l >> 4;
    const int b  = blockIdx.y;
    const int kz = blockIdx.z;
    const int q0 = blockIdx.x * 64;
    const int qs = q0 + s * 16 + lo;
    const int kzoff = kz * KPG;
    const int NCH = KPG / 16;            // 32 chunks of 16 keys

    // ---- staging source addresses (per lane, bytes). Each wave stages
    // 1 KB per stream per chunk (3 DMAs), LDS dest = wave base + l*16. ----
    // K: wave s covers chunk-local key rows s*4 .. s*4+3 (4 x 256B).
    //    Source col pre-swizzled by ((key&7)<<4); LDS stays linear.
    const int keyS = s * 4 + (l >> 4);               // chunk-local key row
    const char* srcK = (const char*)Kb + ((size_t)(b * C_ + kzoff) + keyS) * 256
                       + (((l & 15) * 16) ^ ((keyS & 7) << 4));
    // V: wave s covers d rows s*32 .. s*32+31 (32 x 32B); lane = half-row.
    const int dS = s * 32 + (l >> 1);
    const char* srcV = (const char*)Vt + (size_t)(b * IND + dS) * (C_ * 2)
                       + (size_t)kzoff * 2 + (l & 1) * 16;
    // adj: wave s covers q rows s*16 .. s*16+15 (16 x 64B); lane = quarter.
    const int qS = s * 16 + (l >> 2);
    const char* srcA = (const char*)adj
                       + ((size_t)(b * C_ + q0 + qS) * C_ + kzoff) * 4
                       + (l & 3) * 16;

#if __has_builtin(__builtin_amdgcn_global_load_lds)
#define GLL(gp, lp) __builtin_amdgcn_global_load_lds( \
    (const __attribute__((address_space(1))) unsigned int*)(gp), \
    (__attribute__((address_space(3))) unsigned int*)(lp), 16, 0, 0)
#else
#define GLL(gp, lp) (void)(gp)   // host-pass placeholder
#endif

    auto stage = [&](int c, int buf) {
        GLL(srcK + (size_t)c * 4096, Ksm[buf] + s * 1024);   // keys advance 16*256B
        GLL(srcV + (size_t)c * 32,   Vsm[buf] + s * 1024);   // keys advance 16*2B
        GLL(srcA + (size_t)c * 64,   Asm[buf] + s * 1024);   // keys advance 16*4B
    };

    // qf loaded FIRST, then stage(0), then stage(1); sched_barrier(0)
    // fences pin issue order so the c=0 vmcnt(3) retires exactly
    // qf(4) + stage0(3), keeping stage1's 3 in flight.
    short8 qf[4];
#pragma unroll
    for (int h = 0; h < 4; ++h)
        qf[h] = *(const short8*)(Qb + ((size_t)(b * C_) + qs) * IND + h * 32 + hi * 8);
    __builtin_amdgcn_sched_barrier(0);
    stage(0, 0);
    __builtin_amdgcn_sched_barrier(0);
    stage(1, 1);
    __builtin_amdgcn_sched_barrier(0);

    f4t acc[4][2];
#pragma unroll
    for (int h = 0; h < 4; ++h) { acc[h][0] = 0.f; acc[h][1] = 0.f; }
    float ls[4] = {0.f, 0.f, 0.f, 0.f};

    const int x7 = (lo & 7) << 4;        // K read swizzle (inverse of source)

    auto computeC = [&](int buf) {
        const char* Kl = Ksm[buf];
        const char* Vl = Vsm[buf];
        const char* Al = Asm[buf];
        short8 kf[4];
#pragma unroll
        for (int h = 0; h < 4; ++h)
            kf[h] = *(const short8*)(Kl + lo * 256 + ((h * 64 + hi * 16) ^ x7));
        s4t vf[8];
#pragma unroll
        for (int h = 0; h < 4; ++h) {
            vf[h * 2]     = *(const s4t*)(Vl + (h * 32 + lo) * 32 + hi * 8);
            vf[h * 2 + 1] = *(const s4t*)(Vl + (h * 32 + 16 + lo) * 32 + hi * 8);
        }
        const f4t av = *(const f4t*)(Al + (s * 16 + lo) * 64 + hi * 16);
#pragma unroll
        for (int h = 0; h < 4; ++h) {
            f4t st4 = MFMA32(kf[h], qf[h], (f4t)0.f);
            float p[4];
#pragma unroll
            for (int r = 0; r < 4; ++r) {
                const float a = st4[r] * av[r];          // adj gate (pre-leaky)
                const float m = fmaxf(a, 0.2f * a);      // LeakyReLU(0.2)
                p[r] = exp2f(m);                         // e^s (L2E pre-folded)
                ls[h] += p[r];
            }
            const s4t pp = pack4_bf16(p[0], p[1], p[2], p[3]);
            acc[h][0] = MFMA16(pp, vf[h * 2], acc[h][0]);
            acc[h][1] = MFMA16(pp, vf[h * 2 + 1], acc[h][1]);
        }
    };

    for (int c = 0; c < NCH; ++c) {
        // counted wait: retire chunk c's 3 DMAs (older), keep chunk c+1's
        // 3 in flight. Last chunk: drain. Then raw barrier.
        if (c + 1 < NCH) { asm volatile("s_waitcnt vmcnt(3)" ::: "memory"); }
        else             { asm volatile("s_waitcnt vmcnt(0)" ::: "memory"); }
        __builtin_amdgcn_sched_barrier(0);
        __builtin_amdgcn_s_barrier();
        __builtin_amdgcn_sched_barrier(0);

        computeC(c & 1);

        // all our ds_reads of buf[c&1] retired, fence + barrier before
        // any wave's DMA may overwrite buf[c&1]
        asm volatile("s_waitcnt lgkmcnt(0)" ::: "memory");
        __builtin_amdgcn_sched_barrier(0);
        __builtin_amdgcn_s_barrier();
        __builtin_amdgcn_sched_barrier(0);
        if (c + 2 < NCH) stage(c + 2, c & 1);
    }

    // reduce l over the 4 lane-groups (k quarters) within the wave
#pragma unroll
    for (int h = 0; h < 4; ++h) {
        ls[h] += __shfl_xor(ls[h], 16, 64);
        ls[h] += __shfl_xor(ls[h], 32, 64);
    }

    const size_t BHC   = (size_t)B_ * H_ * C_;
    const size_t obase = (size_t)kz * BHC;

    // each lane writes l for head=hi, q=qs
    const float lw = (hi == 0) ? ls[0] : (hi == 1) ? ls[1] : (hi == 2) ? ls[2] : ls[3];
    lpart[obase + (size_t)(b * H_ + hi) * C_ + qs] = lw;

    // O: PV C-layout: lane owns q = q0+s*16+hi*4+r, d = h*32+dh*16+lo
#pragma unroll
    for (int h = 0; h < 4; ++h) {
        const size_t rb = obase + (size_t)(b * H_ + h) * C_ + q0 + s * 16 + hi * 4;
#pragma unroll
        for (int dh = 0; dh < 2; ++dh)
#pragma unroll
            for (int r = 0; r < 4; ++r)
                Opart[(rb + r) * D_ + dh * 16 + lo] = acc[h][dh][r];
    }
#undef GLL
}

// ---------------------------------------------------------------------------
// K3: combine split-K partials -> AOb (bf16):  AOb = (sum O_kz)/(sum l_kz)
__global__ __launch_bounds__(256) void combine_kernel(
    const float* __restrict__ Opart, const float* __restrict__ lpart,
    unsigned short* __restrict__ AOb)
{
    const int cid = blockIdx.x * 256 + threadIdx.x;   // 0 .. 524287
    const int j   = cid & 7;                          // float4 chunk of D=32
    const int idx = cid >> 3;                         // (b*H+h)*C + q
    const int q  = idx & (C_ - 1);
    const int bh = idx >> 11;
    const int h  = bh & (H_ - 1);
    const int b  = bh >> 2;
    const size_t BHC = (size_t)B_ * H_ * C_;

    float4 acc = {0.f, 0.f, 0.f, 0.f};
    float lsum = 0.f;
#pragma unroll
    for (int kz = 0; kz < KSPLIT; ++kz) {
        const size_t base = (size_t)kz * BHC + idx;
        lsum += lpart[base];
        const float4 v = *(const float4*)(Opart + base * D_ + j * 4);
        acc.x += v.x; acc.y += v.y; acc.z += v.z; acc.w += v.w;
    }
    const float inv = 1.f / lsum;
    us4 o;
    o[0] = f2bf(acc.x * inv); o[1] = f2bf(acc.y * inv);
    o[2] = f2bf(acc.z * inv); o[3] = f2bf(acc.w * inv);
    *(us4*)(AOb + ((size_t)(b * C_) + q) * IND + h * D_ + j * 4) = o;
}

// ---------------------------------------------------------------------------
// K4: output projection via MFMA (transposed-compute -> coalesced float4
// stores with fused bias). Block = 256 = 4 waves = 4 N-quarters; 16 tokens
// per block, grid 1024 -> 4096 waves.
__global__ __launch_bounds__(256) void out_proj_kernel(
    const unsigned short* __restrict__ AOb, const unsigned short* __restrict__ Wtb,
    const float* __restrict__ bo, float* __restrict__ out)
{
    const int t  = threadIdx.x;
    const int w  = t >> 6;               // N-quarter
    const int l  = t & 63;
    const int lo = l & 15, hi = l >> 4;
    const int tok0 = blockIdx.x * 16;

    short8 af[4];
    const unsigned short* arow = AOb + (size_t)(tok0 + lo) * IND;
#pragma unroll
    for (int kc = 0; kc < 4; ++kc)
        af[kc] = *(const short8*)(arow + kc * 32 + hi * 8);

    const unsigned short* wbase = Wtb + (size_t)384 * IND;
#pragma unroll
    for (int tt = 0; tt < 2; ++tt) {
        const int n0 = w * 32 + tt * 16;
        short8 wf[4];
#pragma unroll
        for (int kc = 0; kc < 4; ++kc)
            wf[kc] = *(const short8*)(wbase + (size_t)(n0 + lo) * IND +
                                      kc * 32 + hi * 8);
        f4t acc = 0.f;
#pragma unroll
        for (int kc = 0; kc < 4; ++kc) acc = MFMA32(wf[kc], af[kc], acc);
        const f4t bv = *(const f4t*)(bo + n0 + hi * 4);
        float4 o;
        o.x = acc[0] + bv[0]; o.y = acc[1] + bv[1];
        o.z = acc[2] + bv[2]; o.w = acc[3] + bv[3];
        *(float4*)(out + (size_t)(tok0 + lo) * IND + n0 + hi * 4) = o;
    }
}

// ---------------------------------------------------------------------------
extern "C" void kernel_launch(void* const* d_in, const int* in_sizes, int n_in,
                              void* d_out, int out_size, void* d_ws, size_t ws_size,
                              hipStream_t stream) {
    const float* x   = (const float*)d_in[0];
    const float* adj = (const float*)d_in[1];
    const float* Wq  = (const float*)d_in[2];
    const float* Wk  = (const float*)d_in[3];
    const float* Wv  = (const float*)d_in[4];
    const float* Wo  = (const float*)d_in[5];
    const float* bo  = (const float*)d_in[6];
    float* out = (float*)d_out;

    // workspace (bf16 unless noted): Wtb 128KB; Qb/Kb/Vt 4.2MB each;
    // AOb 4.2MB; Opart fp32 33.6MB; lpart fp32 1MB  -> ~47.5 MB total
    unsigned short* Wtb = (unsigned short*)d_ws;
    unsigned short* Qb  = Wtb + (size_t)512 * IND;
    unsigned short* Kb  = Qb + (size_t)M_ * IND;
    unsigned short* Vt  = Kb + (size_t)M_ * IND;
    unsigned short* AOb = Vt + (size_t)M_ * IND;
    float* Opart = (float*)(AOb + (size_t)M_ * IND);
    float* lpart = Opart + (size_t)KSPLIT * B_ * H_ * C_ * D_;

    hipLaunchKernelGGL(prep_w_kernel, dim3(32), dim3(256), 0, stream,
                       Wq, Wk, Wv, Wo, Wtb);
    hipLaunchKernelGGL(qkv_proj_kernel, dim3(M_ / 16, 2), dim3(192), 0, stream,
                       x, Wtb, Qb, Kb, Vt);
    hipLaunchKernelGGL(attn_kernel, dim3(C_ / 64, B_, KSPLIT), dim3(256), 0, stream,
                       Qb, Kb, Vt, adj, Opart, lpart);
    hipLaunchKernelGGL(combine_kernel, dim3(B_ * H_ * C_ * 8 / 256), dim3(256), 0, stream,
                       Opart, lpart, AOb);
    hipLaunchKernelGGL(out_proj_kernel, dim3(M_ / 16), dim3(256), 0, stream,
                       AOb, Wtb, bo, out);
}